// Round 8
// baseline (315.239 us; speedup 1.0000x reference)
//
#include <hip/hip_runtime.h>
#include <hip/hip_bf16.h>

typedef __hip_bfloat16 bf16;
typedef __attribute__((ext_vector_type(8))) short short8;
typedef __attribute__((ext_vector_type(4))) float f32x4;

constexpr int IMG_H = 128;
constexpr int IMG_W = 256;
constexpr int HW    = IMG_H * IMG_W;   // 32768
constexpr int BB    = 2;
constexpr int CC    = 48;
constexpr int C3    = 144;
constexpr int XPW   = 268;             // QC padded width (x in [-6, 261])
constexpr int XOFF  = 6;

// ---------------- fp32 workspace layout (element offsets) ----------------
constexpr int WO_QKVL_W = 0;        // 6912
constexpr int WO_QKVR_W = 6912;     // 6912
constexpr int WO_DWL_W  = 13824;    // 1296
constexpr int WO_DWR_W  = 15120;    // 1296
constexpr int WO_C1_W   = 16416;    // 2304
constexpr int WO_C2_W   = 18720;    // 2304
constexpr int WO_QKVL_B = 21024;    // 144
constexpr int WO_QKVR_B = 21168;    // 144
constexpr int WO_DWL_B  = 21312;    // 144
constexpr int WO_DWR_B  = 21456;    // 144
constexpr int WO_C1_B   = 21600;    // 48
constexpr int WO_C2_B   = 21648;    // 48  (= C1_B + 48, contiguous)
constexpr int WO_LN1W   = 21696;    // 48
constexpr int WO_LN1B   = 21744;    // 48
constexpr int WO_LN2W   = 21792;    // 48
constexpr int WO_LN2B   = 21840;    // 48
constexpr int WO_TEMP   = 21888;    // 3 (pad to 21952)
constexpr int WO_WQ     = 21952;    // 13824 (convQ_w fp32)
constexpr int WO_D0W    = 35776;    // 82944
constexpr int WO_D1W    = 118720;   // 82944
constexpr int WO_D2W    = 201664;   // 82944
constexpr int WO_BQ     = 284608;   // 48
constexpr int WO_B0     = 284656;   // 96
constexpr int WO_B1     = 284752;   // 96
constexpr int WO_B2     = 284848;   // 96
constexpr int WO_WPACK  = 284944;   // bf16 region! 124416 bf16 = 62208 floats
constexpr int WO_EFFB   = 409360;   // 48 (pad to 409424)
constexpr int WO_NQ     = 409424;   // 96 (sum of squares)
constexpr int WO_NKL    = 409520;   // 96
constexpr int WO_NKR    = 409616;   // 96
constexpr int WO_AR2L   = 409712;   // 1536
constexpr int WO_AL2R   = 411248;   // 1536
constexpr int WO_M1     = 412800;   // 4608 (fold of conv1 into A_r2l, per b)
constexpr int WO_M2     = 417408;   // 4608 (= M1 + 4608, contiguous)
constexpr int WO_WQP    = 422016;   // bf16 region! 18432 bf16 = 9216 floats
constexpr int WO_PART   = 431232;   // 98304 (logits partials 12*32*256)
// end 529536 floats = 2,118,144 B

constexpr size_t ACT_BASE_BYTES = 2118144;

// bf16 activation region (element offsets)
constexpr size_t A_P  = 0;          // pre scratch (B*144*HW); later reused for qh
constexpr size_t A_Q1 = 9437184;    // qkv_l (B*144*HW)
constexpr size_t A_Q2 = 18874368;   // qkv_r (B*144*HW)
constexpr size_t A_QC = 28311552;   // QC (6586368)
// end 34897920 elems = 69.8 MB; total ws use ~72 MB

// ---------------- prep ----------------
struct PrepArgs {
  const void* src[25];
  int dst[25];
  int n[25];
};

__device__ __forceinline__ bool probe_bf16(const void* ln1w) {
  return ((const unsigned short*)ln1w)[0] == 0x3F80;
}

__global__ __launch_bounds__(256) void prep_k(PrepArgs a, float* __restrict__ wsf) {
  bool isb = probe_bf16(a.src[12]);
  int t = blockIdx.y;
  int i = blockIdx.x * 256 + threadIdx.x;
  if (i < a.n[t]) {
    float v = isb ? __bfloat162float(((const bf16*)a.src[t])[i])
                  : ((const float*)a.src[t])[i];
    wsf[a.dst[t] + i] = v;
  }
}

// fold convQ into dilated-conv weights, bf16, MFMA B-frag order, taps
// reordered by dy-group: ti = trow==0 ? (2-d)*3+dxi : trow==1 ? 9+d*3+dxi
//                                   : 18+d*3+dxi
__global__ __launch_bounds__(256) void effw2_k(const float* __restrict__ wsf,
                                               bf16* __restrict__ wpack) {
  int d  = blockIdx.x / 96;
  int ci = blockIdx.x % 96;
  __shared__ float wds[864];
  __shared__ float wqs[48 * 97];
  const int wdb = (d == 0) ? WO_D0W : (d == 1) ? WO_D1W : WO_D2W;
  for (int idx = threadIdx.x; idx < 864; idx += 256) {
    int m = idx / 9, tt = idx % 9;
    wds[idx] = wsf[wdb + (m * 96 + ci) * 9 + tt];
  }
  for (int idx = threadIdx.x; idx < 4608; idx += 256) {
    int co = idx / 96, m = idx % 96;
    wqs[co * 97 + m] = wsf[WO_WQ + co * 288 + d * 96 + m];
  }
  __syncthreads();
  int tco = threadIdx.x;
  if (tco < 432) {
    int t = tco / 48, co = tco % 48;
    float s = 0.f;
#pragma unroll 8
    for (int m = 0; m < 96; ++m) s += wqs[co * 97 + m] * wds[m * 9 + t];
    int trow = t / 3, dxi = t % 3;
    int ti = (trow == 0) ? (2 - d) * 3 + dxi
           : (trow == 1) ? 9 + d * 3 + dxi
                         : 18 + d * 3 + dxi;
    int kc = ci >> 5, j = ci & 7;
    int L = ((ci & 31) >> 3) * 16 + (co & 15);
    int nt = co >> 4;
    int f = (ti * 3 + kc) * 3 + nt;
    wpack[(size_t)f * 512 + L * 8 + j] = __float2bfloat16(s);
  }
}

__global__ __launch_bounds__(64) void effb_k(const float* __restrict__ wsf,
                                             float* __restrict__ effb) {
  int co = threadIdx.x;
  if (co >= 48) return;
  float s = wsf[WO_BQ + co];
  for (int m = 0; m < 96; ++m) {
    s += wsf[WO_WQ + co * 288 + m]       * wsf[WO_B0 + m];
    s += wsf[WO_WQ + co * 288 + 96 + m]  * wsf[WO_B1 + m];
    s += wsf[WO_WQ + co * 288 + 192 + m] * wsf[WO_B2 + m];
  }
  effb[co] = s;
}

// pack qkv 1x1 weights into MFMA B-frag order, K padded 48->64
__global__ __launch_bounds__(256) void wqp_k(const float* __restrict__ wsf,
                                             bf16* __restrict__ wqp) {
  int idx = blockIdx.x * 256 + threadIdx.x;
  if (idx >= 18432) return;
  int side = idx / 9216;
  int rem = idx % 9216;
  int nt = rem / 1024;
  int kt = (rem / 512) % 2;
  int e  = rem % 512;
  int L = e >> 3, j = e & 7;
  int o = nt * 16 + (L & 15);
  int kp = kt * 32 + (L >> 4) * 8 + j;
  int g = kp >> 4, r = kp & 15;
  float val = 0.f;
  if (r < 12) {
    int c = g * 12 + r;
    val = wsf[(side ? WO_QKVR_W : WO_QKVL_W) + o * 48 + c];
  }
  wqp[idx] = __float2bfloat16(val);
}

// ---------------- fused LN2d + qkv 1x1 (48->144) via MFMA, XN in LDS --------
// grid 1024 (one side per launch); block 256 thr, 64 px.
__global__ __launch_bounds__(256) void lnqkv_k(
    const void* __restrict__ x, const void* __restrict__ probe,
    const float* __restrict__ lnw, const float* __restrict__ lnb,
    const bf16* __restrict__ wqp_side, const float* __restrict__ qb,
    bf16* __restrict__ pre) {
  __shared__ __align__(16) unsigned char LDSU[21504 + 18432];
  bf16* XNs = (bf16*)LDSU;                 // [64 px][72 kpad] bf16
  float2* red = (float2*)(LDSU + 9216);    // [4][64]
  bf16* Cs = (bf16*)LDSU;                  // [144][66] (aliases XNs later)
  bf16* W = (bf16*)(LDSU + 21504);         // 18432 B
  int tid = threadIdx.x;
  for (int i = tid; i < 1152; i += 256)
    ((uint4*)W)[i] = ((const uint4*)wqp_side)[i];

  // phase 1: LN (wave w owns channels 12w..12w+11 for all 64 px)
  int px = tid & 63;
  int w = tid >> 6;
  int p = blockIdx.x * 64 + px;
  int b = p >> 15;
  int pix = p & (HW - 1);
  size_t base = (size_t)b * CC * HW + pix;
  float v[12];
  if (probe_bf16(probe)) {
    const bf16* xp = (const bf16*)x + base;
#pragma unroll
    for (int c = 0; c < 12; ++c)
      v[c] = __bfloat162float(xp[(size_t)(w * 12 + c) * HW]);
  } else {
    const float* xp = (const float*)x + base;
#pragma unroll
    for (int c = 0; c < 12; ++c) v[c] = xp[(size_t)(w * 12 + c) * HW];
  }
  float s = 0.f, s2 = 0.f;
#pragma unroll
  for (int c = 0; c < 12; ++c) { s += v[c]; s2 += v[c] * v[c]; }
  red[w * 64 + px] = make_float2(s, s2);
  __syncthreads();
  float S = 0.f, S2 = 0.f;
#pragma unroll
  for (int i = 0; i < 4; ++i) {
    float2 r2 = red[i * 64 + px];
    S += r2.x; S2 += r2.y;
  }
  float mu = S * (1.f / 48.f);
  float var = S2 * (1.f / 48.f) - mu * mu;
  float rs = rsqrtf(var + 1e-6f);
  bf16 o16[16];
#pragma unroll
  for (int c = 0; c < 12; ++c)
    o16[c] = __float2bfloat16((v[c] - mu) * rs * lnw[w * 12 + c] + lnb[w * 12 + c]);
#pragma unroll
  for (int c = 12; c < 16; ++c) o16[c] = __float2bfloat16(0.f);
  // padded k-slot: channel c=w*12+cc -> kp = w*16+cc; zeros in cc 12..15
  *(uint4*)(XNs + px * 72 + w * 16) = *(uint4*)(o16);
  *(uint4*)(XNs + px * 72 + w * 16 + 8) = *(uint4*)(o16 + 8);
  __syncthreads();

  // phase 2: MFMA. wave w = px tile [w*16, w*16+16)
  int L = tid & 63;
  int lo = L & 15, hi = L >> 4;
  const bf16* arow = XNs + (size_t)(w * 16 + lo) * 72 + hi * 8;
  short8 a0 = *(const short8*)(arow);
  short8 a1 = *(const short8*)(arow + 32);
  __syncthreads();   // XNs/red dead; Cs may overwrite
#pragma unroll
  for (int nt = 0; nt < 9; ++nt) {
    float bvv = qb[nt * 16 + lo];
    f32x4 acc = {bvv, bvv, bvv, bvv};
    acc = __builtin_amdgcn_mfma_f32_16x16x32_bf16(
        a0, *(const short8*)(W + (nt * 2 + 0) * 512 + L * 8), acc, 0, 0, 0);
    acc = __builtin_amdgcn_mfma_f32_16x16x32_bf16(
        a1, *(const short8*)(W + (nt * 2 + 1) * 512 + L * 8), acc, 0, 0, 0);
#pragma unroll
    for (int r = 0; r < 4; ++r)
      Cs[(nt * 16 + lo) * 66 + w * 16 + hi * 4 + r] = __float2bfloat16(acc[r]);
  }
  __syncthreads();
  int pix0 = (blockIdx.x * 64) & (HW - 1);
#pragma unroll
  for (int pass = 0; pass < 18; ++pass) {
    int o = pass * 8 + (tid >> 5);
    int px2 = (tid & 31) * 2;
    bf16 t2[2];
    t2[0] = Cs[o * 66 + px2];
    t2[1] = Cs[o * 66 + px2 + 1];
    *(unsigned*)(pre + ((size_t)(b * C3 + o)) * HW + pix0 + px2) = *(unsigned*)t2;
  }
}

// ---------------- depthwise 3x3, pad 1 — vectorized 8 px/thread ----------------
__global__ __launch_bounds__(256) void dw_k(
    const bf16* __restrict__ in, const float* __restrict__ w9,
    const float* __restrict__ bias, bf16* __restrict__ out) {
  int gid = blockIdx.x;
  int yt = gid & 15;
  int c = (gid >> 4) % C3;
  int b = gid / (16 * C3);
  int ry = threadIdx.x >> 5, xi = threadIdx.x & 31;
  int y = yt * 8 + ry;
  int x0 = xi * 8;
  const bf16* base = in + ((size_t)(b * C3 + c)) * HW;
  float wv[9];
#pragma unroll
  for (int t = 0; t < 9; ++t) wv[t] = w9[c * 9 + t];
  float bz = bias[c];
  float acc[8];
#pragma unroll
  for (int i = 0; i < 8; ++i) acc[i] = bz;
#pragma unroll
  for (int ky = 0; ky < 3; ++ky) {
    int yy = y + ky - 1;
    if ((unsigned)yy >= (unsigned)IMG_H) continue;
    const bf16* row = base + yy * IMG_W + x0;
    uint4 m = *(const uint4*)(row);
    float f[10];
    f[0] = (x0 > 0) ? __bfloat162float(row[-1]) : 0.f;
    f[9] = (x0 + 8 < IMG_W) ? __bfloat162float(row[8]) : 0.f;
    f[1] = __uint_as_float(m.x << 16);
    f[2] = __uint_as_float(m.x & 0xFFFF0000u);
    f[3] = __uint_as_float(m.y << 16);
    f[4] = __uint_as_float(m.y & 0xFFFF0000u);
    f[5] = __uint_as_float(m.z << 16);
    f[6] = __uint_as_float(m.z & 0xFFFF0000u);
    f[7] = __uint_as_float(m.w << 16);
    f[8] = __uint_as_float(m.w & 0xFFFF0000u);
    float w0 = wv[ky * 3], w1 = wv[ky * 3 + 1], w2 = wv[ky * 3 + 2];
#pragma unroll
    for (int i = 0; i < 8; ++i)
      acc[i] += w0 * f[i] + w1 * f[i + 1] + w2 * f[i + 2];
  }
  bf16 o[8];
#pragma unroll
  for (int i = 0; i < 8; ++i) o[i] = __float2bfloat16(acc[i]);
  *(uint4*)(out + ((size_t)(b * C3 + c)) * HW + y * IMG_W + x0) = *(uint4*)o;
}

// ---------------- channel-last transpose of Q channels ----------------
__global__ __launch_bounds__(256) void qc_k(const bf16* __restrict__ q1,
                                            const bf16* __restrict__ q2,
                                            bf16* __restrict__ qc) {
  int b = blockIdx.x >> 7;
  int y = blockIdx.x & 127;
  int half = blockIdx.y;
  int tid = threadIdx.x;
  int x0 = half * 128;
  int px = tid & 127;
  int cig = tid >> 7;
  __shared__ __align__(16) bf16 T[128][100];
#pragma unroll 8
  for (int k = 0; k < 48; ++k) {
    int ci = cig * 48 + k;
    const bf16* src = (ci < 48)
        ? q1 + (((size_t)(b * C3 + ci)) * IMG_H + y) * IMG_W
        : q2 + (((size_t)(b * C3 + ci - 48)) * IMG_H + y) * IMG_W;
    T[px][ci] = src[x0 + px];
  }
  __syncthreads();
  size_t rowbase = ((size_t)(b * IMG_H + y)) * XPW * 96 + (size_t)half * 12864;
#pragma unroll 1
  for (int i = 0; i < 13; ++i) {
    int e4 = i * 256 + tid;
    if (e4 >= 3216) break;
    int e = e4 * 4;
    int xp = (e + half * 12864) / 96;
    int ci = (e + half * 12864) % 96;
    int x = xp - XOFF;
    uint2 val;
    if ((unsigned)x < (unsigned)IMG_W) {
      val = *(const uint2*)(&T[x - x0][ci]);
    } else {
      val.x = 0u; val.y = 0u;
    }
    *(uint2*)(qc + rowbase + e) = val;
  }
}

// ---------------- tri-dilation conv via MFMA v3 ----------------
// 1-D grid 1536, 128 threads (2 waves x 64 px = 128 px/block), co-split x3.
// XCD swizzle: xcd=bid&7 owns y-band [16*xcd, 16*xcd+16).
// taps ordered by dy group (matches effw2 ti): g=ti/3:
//   g<3: D=6-2g, dy=-D; g<6: D=2(g-2), dy=0; else D=2(g-5), dy=+D; dx=(ti%3-1)*D
__global__ __launch_bounds__(128) void dil_mfma_k(
    const bf16* __restrict__ qc, const bf16* __restrict__ wp,
    const float* __restrict__ effb, bf16* __restrict__ qh) {
  __shared__ __align__(16) unsigned char LDSU[8768];  // dbuf 6144 | Cs 16*137*4
  bf16* Wb = (bf16*)LDSU;
  float* Cs = (float*)LDSU;
  int bid = blockIdx.x;
  int xcd = bid & 7;
  int slot = bid >> 3;                  // 0..191
  int y = xcd * 16 + (slot & 15);
  int rest = slot >> 4;                 // 0..11
  int xt = rest & 1;
  int b = (rest >> 1) & 1;
  int cg = rest >> 2;                   // 0..2 (co group of 16)
  int tid = threadIdx.x;                // 0..127
  int L = tid & 63;
  int w = tid >> 6;                     // 0..1
  int lo = L & 15, hi = L >> 4;
  int x0 = xt * 128;

  f32x4 acc[4];
  {
    float bv = effb[cg * 16 + lo];
#pragma unroll
    for (int s = 0; s < 4; ++s) acc[s] = {bv, bv, bv, bv};
  }
  const size_t abase =
      ((size_t)(b * IMG_H + y) * XPW + XOFF + x0 + w * 64 + lo) * 96 + hi * 8;

  // stage tap 0 (3 KB: kc 0..2, nt=cg)
  for (int t = tid; t < 192; t += 128) {
    int kc = t >> 6, e = t & 63;
    ((uint4*)(Wb))[kc * 64 + e] =
        *((const uint4*)(wp + ((size_t)(0 * 3 + kc) * 3 + cg) * 512) + e);
  }
  __syncthreads();

#pragma unroll 1
  for (int ti = 0; ti < 27; ++ti) {
    if (ti + 1 < 27) {
      int tn = ti + 1;
      for (int t = tid; t < 192; t += 128) {
        int kc = t >> 6, e = t & 63;
        ((uint4*)(Wb + (tn & 1) * 1536))[kc * 64 + e] =
            *((const uint4*)(wp + ((size_t)(tn * 3 + kc) * 3 + cg) * 512) + e);
      }
    }
    int g = ti / 3, dxi = ti - g * 3;
    int D = (g < 3) ? (6 - 2 * g) : (g < 6) ? (2 * (g - 2)) : (2 * (g - 5));
    int dy = (g < 3) ? -D : (g < 6) ? 0 : D;
    int dx = (dxi - 1) * D;
    if ((unsigned)(y + dy) < (unsigned)IMG_H) {   // wave-uniform
      const bf16* wb = Wb + (ti & 1) * 1536;
      const bf16* ap = qc + abase + ((long)dy * XPW + dx) * 96;
#pragma unroll
      for (int kc = 0; kc < 3; ++kc) {
        short8 wv = *(const short8*)(wb + kc * 512 + L * 8);
#pragma unroll
        for (int s = 0; s < 4; ++s) {
          short8 a = *(const short8*)(ap + kc * 32 + s * 1536);
          acc[s] = __builtin_amdgcn_mfma_f32_16x16x32_bf16(a, wv, acc[s], 0, 0, 0);
        }
      }
    }
    __syncthreads();
  }

  // epilogue: Cs[co16][137], then coalesced bf16 stores
#pragma unroll
  for (int s = 0; s < 4; ++s)
#pragma unroll
    for (int r = 0; r < 4; ++r)
      Cs[lo * 137 + w * 64 + s * 16 + hi * 4 + r] = acc[s][r];
  __syncthreads();
#pragma unroll
  for (int p = 0; p < 2; ++p) {
    int e = (p * 128 + tid) * 8;
    int co = e >> 7;
    int px = e & 127;
    const float* srcp = &Cs[co * 137 + px];
    bf16 tmp[8];
#pragma unroll
    for (int i2 = 0; i2 < 8; ++i2) tmp[i2] = __float2bfloat16(srcp[i2]);
    *(uint4*)(qh + (((size_t)(b * CC + cg * 16 + co)) * IMG_H + y) * IMG_W +
              x0 + px) = *(uint4*)tmp;
  }
}

// ---------------- reductions for attention ----------------
__device__ __forceinline__ float wave_sum(float v) {
#pragma unroll
  for (int off = 32; off > 0; off >>= 1) v += __shfl_down(v, off, 64);
  return v;
}

__device__ __forceinline__ float blo(unsigned u) {
  return __uint_as_float(u << 16);
}
__device__ __forceinline__ float bhi(unsigned u) {
  return __uint_as_float(u & 0xFFFF0000u);
}

__global__ __launch_bounds__(256) void rownorm_k(
    const bf16* __restrict__ qh, const bf16* __restrict__ qkvl,
    const bf16* __restrict__ qkvr, float* __restrict__ nq,
    float* __restrict__ nkl, float* __restrict__ nkr) {
  int id = blockIdx.x;
  int which = id / 96;
  int rid = id % 96;
  int b = rid / 48;
  int c = rid % 48;
  const bf16* ptr = (which == 0) ? qh + ((size_t)(b * CC + c)) * HW
                  : (which == 1) ? qkvl + ((size_t)(b * C3 + 48 + c)) * HW
                                 : qkvr + ((size_t)(b * C3 + 48 + c)) * HW;
  float s = 0.f;
#pragma unroll 2
  for (int it = 0; it < 16; ++it) {
    int n0 = (it * 256 + threadIdx.x) * 8;
    uint4 u = *(const uint4*)(ptr + n0);
    float a0 = blo(u.x), a1 = bhi(u.x), a2 = blo(u.y), a3 = bhi(u.y);
    float a4 = blo(u.z), a5 = bhi(u.z), a6 = blo(u.w), a7 = bhi(u.w);
    s += a0 * a0 + a1 * a1 + a2 * a2 + a3 * a3 + a4 * a4 + a5 * a5 +
         a6 * a6 + a7 * a7;
  }
  s = wave_sum(s);
  __shared__ float red[4];
  if ((threadIdx.x & 63) == 0) red[threadIdx.x >> 6] = s;
  __syncthreads();
  if (threadIdx.x == 0) {
    float tot = red[0] + red[1] + red[2] + red[3];
    float* dst = (which == 0) ? nq : (which == 1) ? nkl : nkr;
    dst[rid] = tot;
  }
}

// ---------------- logits via MFMA Gram: grid (12, 32) ----------------
__global__ __launch_bounds__(256) void logits_mfma_k(
    const bf16* __restrict__ qh, const bf16* __restrict__ qkvl,
    const bf16* __restrict__ qkvr, float* __restrict__ part) {
  int abh = blockIdx.x;
  int chunk = blockIdx.y;
  int a = abh / 6;
  int b = (abh / 3) % 2;
  int h = abh % 3;
  int tid = threadIdx.x;
  int L = tid & 63, w = tid >> 6;
  int lo = L & 15, hi = L >> 4;
  const bf16* qrow = qh + ((size_t)(b * CC + h * 16 + lo)) * HW;
  const bf16* krow =
      ((a == 0) ? qkvr : qkvl) + ((size_t)(b * C3 + 48 + h * 16 + lo)) * HW;
  int px0 = chunk * 1024 + w * 256 + hi * 8;
  f32x4 acc = {0.f, 0.f, 0.f, 0.f};
#pragma unroll
  for (int s = 0; s < 8; ++s) {
    short8 av = *(const short8*)(qrow + px0 + s * 32);
    short8 bv = *(const short8*)(krow + px0 + s * 32);
    acc = __builtin_amdgcn_mfma_f32_16x16x32_bf16(av, bv, acc, 0, 0, 0);
  }
  __shared__ float red[4][256];
#pragma unroll
  for (int r = 0; r < 4; ++r) red[w][(hi * 4 + r) * 16 + lo] = acc[r];
  __syncthreads();
  float sum = red[0][tid] + red[1][tid] + red[2][tid] + red[3][tid];
  part[((size_t)abh * 32 + chunk) * 256 + tid] = sum;
}

__global__ __launch_bounds__(256) void logits_red_k(
    const float* __restrict__ part, const float* __restrict__ nq,
    const float* __restrict__ nkl, const float* __restrict__ nkr,
    const float* __restrict__ temp, float* __restrict__ logr2l,
    float* __restrict__ logl2r) {
  int abh = blockIdx.x;
  int a = abh / 6, b = (abh / 3) % 2, h = abh % 3;
  int t = threadIdx.x;
  int i = t >> 4, j = t & 15;
  float s = 0.f;
  const float* p = part + (size_t)abh * 32 * 256 + t;
#pragma unroll 8
  for (int c = 0; c < 32; ++c) s += p[c * 256];
  float qn = fmaxf(sqrtf(nq[b * 48 + h * 16 + i]), 1e-12f);
  float kn = fmaxf(sqrtf(((a == 0) ? nkr : nkl)[b * 48 + h * 16 + j]), 1e-12f);
  float val = s / (qn * kn) * temp[h];
  ((a == 0) ? logr2l : logl2r)[b * 768 + h * 256 + i * 16 + j] = val;
}

// softmax over j (16) + fold conv1/conv2 into A -> M1/M2
__global__ __launch_bounds__(256) void softmaxM_k(float* __restrict__ wsf) {
  int tid = threadIdx.x;
  __shared__ float A1[1536], A2[1536];
  if (tid < 192) {
    const float* p = wsf + ((tid < 96) ? WO_AR2L : WO_AL2R) + (tid % 96) * 16;
    float* dst = ((tid < 96) ? A1 : A2) + (tid % 96) * 16;
    float m = -1e30f;
#pragma unroll
    for (int j = 0; j < 16; ++j) m = fmaxf(m, p[j]);
    float s = 0.f;
    float e[16];
#pragma unroll
    for (int j = 0; j < 16; ++j) {
      e[j] = expf(p[j] - m);
      s += e[j];
    }
    float inv = 1.f / s;
#pragma unroll
    for (int j = 0; j < 16; ++j) dst[j] = e[j] * inv;
  }
  __syncthreads();
#pragma unroll 1
  for (int idx = tid; idx < 4608; idx += 256) {
    int b = idx / 2304;
    int r = idx % 2304;
    int o = r / 48;
    int cp = r % 48;
    int h = cp >> 4, j = cp & 15;
    const float* a1 = &A1[((b * 3 + h) * 16) * 16 + j];
    const float* a2 = &A2[((b * 3 + h) * 16) * 16 + j];
    float s1 = 0.f, s2 = 0.f;
#pragma unroll
    for (int i = 0; i < 16; ++i) {
      s1 += wsf[WO_C1_W + o * 48 + h * 16 + i] * a1[i * 16];
      s2 += wsf[WO_C2_W + o * 48 + h * 16 + i] * a2[i * 16];
    }
    wsf[WO_M1 + idx] = s1;
    wsf[WO_M2 + idx] = s2;
  }
}

// ---------------- fused M@V + residual -> out (both sides, z=side) ----------
__global__ __launch_bounds__(256) void attn_out2_k(
    const bf16* __restrict__ q1, const bf16* __restrict__ q2,
    const void* __restrict__ x1, const void* __restrict__ x2,
    const void* __restrict__ probe, const float* __restrict__ Mall,
    const float* __restrict__ cball, void* __restrict__ out) {
  int side = blockIdx.z;
  const bf16* qkv = side ? q2 : q1;
  const void* x = side ? x2 : x1;
  const float* M = Mall + side * 4608;
  const float* cb = cball + side * 48;
  int tid = threadIdx.x;
  int p = blockIdx.x * 256 + tid;
  int b = __builtin_amdgcn_readfirstlane(p >> 15);
  int pix = p & (HW - 1);
  int o0 = blockIdx.y * 16;
  bool isb = probe_bf16(probe);

  float v[CC];
  const bf16* vb = qkv + ((size_t)(b * C3 + 96)) * HW + pix;
#pragma unroll
  for (int c = 0; c < CC; ++c) v[c] = __bfloat162float(vb[(size_t)c * HW]);

  const float* Mb = M + b * 2304;
  size_t base = (size_t)b * CC * HW + pix;
  float res[16];
#pragma unroll 2
  for (int o = 0; o < 16; ++o) {
    float acc = cb[o0 + o];
    const float* mrow = Mb + (o0 + o) * 48;
#pragma unroll
    for (int c = 0; c < CC; ++c) acc += mrow[c] * v[c];
    res[o] = acc;
  }
  size_t obase = (size_t)side * BB * CC * HW + base + (size_t)o0 * HW;
  if (isb) {
    const bf16* xp = (const bf16*)x + base + (size_t)o0 * HW;
    bf16* op = (bf16*)out + obase;
#pragma unroll
    for (int o = 0; o < 16; ++o)
      op[(size_t)o * HW] =
          __float2bfloat16(res[o] + __bfloat162float(xp[(size_t)o * HW]));
  } else {
    const float* xp = (const float*)x + base + (size_t)o0 * HW;
    float* op = (float*)out + obase;
#pragma unroll
    for (int o = 0; o < 16; ++o) op[(size_t)o * HW] = res[o] + xp[(size_t)o * HW];
  }
}

// ---------------- launch ----------------
extern "C" void kernel_launch(void* const* d_in, const int* in_sizes, int n_in,
                              void* d_out, int out_size, void* d_ws, size_t ws_size,
                              hipStream_t stream) {
  (void)in_sizes; (void)n_in; (void)out_size; (void)ws_size;
  const void* x_l = d_in[0];
  const void* x_r = d_in[1];
  const void* probe = d_in[2];
  float* wsf = (float*)d_ws;
  bf16* wpack = (bf16*)(wsf + WO_WPACK);
  bf16* wqp = (bf16*)(wsf + WO_WQP);
  bf16* act = (bf16*)((char*)d_ws + ACT_BASE_BYTES);
  bf16* P  = act + A_P;
  bf16* Q1 = act + A_Q1;
  bf16* Q2 = act + A_Q2;
  bf16* QC = act + A_QC;
  bf16* qh = P;

  PrepArgs pa;
  const int srcIdx[25] = {6, 8, 10, 12, 22, 24, 7, 9, 11, 13, 23, 25,
                          2, 3, 4, 5, 26, 20, 14, 16, 18, 21, 15, 17, 19};
  const int dstOff[25] = {WO_QKVL_W, WO_QKVR_W, WO_DWL_W, WO_DWR_W, WO_C1_W, WO_C2_W,
                          WO_QKVL_B, WO_QKVR_B, WO_DWL_B, WO_DWR_B, WO_C1_B, WO_C2_B,
                          WO_LN1W, WO_LN1B, WO_LN2W, WO_LN2B, WO_TEMP,
                          WO_WQ, WO_D0W, WO_D1W, WO_D2W, WO_BQ, WO_B0, WO_B1, WO_B2};
  const int ns[25] = {6912, 6912, 1296, 1296, 2304, 2304, 144, 144, 144, 144,
                      48, 48, 48, 48, 48, 48, 3,
                      13824, 82944, 82944, 82944, 48, 96, 96, 96};
  for (int i = 0; i < 25; ++i) {
    pa.src[i] = d_in[srcIdx[i]];
    pa.dst[i] = dstOff[i];
    pa.n[i] = ns[i];
  }
  prep_k<<<dim3(324, 25), 256, 0, stream>>>(pa, wsf);

  effw2_k<<<288, 256, 0, stream>>>(wsf, wpack);
  effb_k<<<1, 64, 0, stream>>>(wsf, wsf + WO_EFFB);
  wqp_k<<<72, 256, 0, stream>>>(wsf, wqp);

  lnqkv_k<<<1024, 256, 0, stream>>>(x_l, probe, wsf + WO_LN1W, wsf + WO_LN1B,
                                    wqp, wsf + WO_QKVL_B, P);
  dw_k<<<BB * C3 * 16, 256, 0, stream>>>(P, wsf + WO_DWL_W, wsf + WO_DWL_B, Q1);
  lnqkv_k<<<1024, 256, 0, stream>>>(x_r, probe, wsf + WO_LN2W, wsf + WO_LN2B,
                                    wqp + 9216, wsf + WO_QKVR_B, P);
  dw_k<<<BB * C3 * 16, 256, 0, stream>>>(P, wsf + WO_DWR_W, wsf + WO_DWR_B, Q2);

  qc_k<<<dim3(BB * IMG_H, 2), 256, 0, stream>>>(Q1, Q2, QC);

  // P dead; qh aliases it
  dil_mfma_k<<<1536, 128, 0, stream>>>(QC, wpack, wsf + WO_EFFB, qh);

  rownorm_k<<<288, 256, 0, stream>>>(qh, Q1, Q2, wsf + WO_NQ,
                                     wsf + WO_NKL, wsf + WO_NKR);
  logits_mfma_k<<<dim3(12, 32), 256, 0, stream>>>(qh, Q1, Q2, wsf + WO_PART);
  logits_red_k<<<12, 256, 0, stream>>>(wsf + WO_PART, wsf + WO_NQ,
                                       wsf + WO_NKL, wsf + WO_NKR,
                                       wsf + WO_TEMP, wsf + WO_AR2L,
                                       wsf + WO_AL2R);
  softmaxM_k<<<1, 256, 0, stream>>>(wsf);

  attn_out2_k<<<dim3(256, 3, 2), 256, 0, stream>>>(
      Q1, Q2, x_l, x_r, probe, wsf + WO_M1, wsf + WO_C1_B, d_out);
}

// Round 9
// 279.990 us; speedup vs baseline: 1.1259x; 1.1259x over previous
//
#include <hip/hip_runtime.h>
#include <hip/hip_bf16.h>

typedef __hip_bfloat16 bf16;
typedef __attribute__((ext_vector_type(8))) short short8;
typedef __attribute__((ext_vector_type(4))) float f32x4;

constexpr int IMG_H = 128;
constexpr int IMG_W = 256;
constexpr int HW    = IMG_H * IMG_W;   // 32768
constexpr int BB    = 2;
constexpr int CC    = 48;
constexpr int C3    = 144;
constexpr int XPW   = 268;             // QC padded width (x in [-6, 261])
constexpr int XOFF  = 6;

// ---------------- fp32 workspace layout (element offsets) ----------------
constexpr int WO_QKVL_W = 0;        // 6912
constexpr int WO_QKVR_W = 6912;     // 6912
constexpr int WO_DWL_W  = 13824;    // 1296
constexpr int WO_DWR_W  = 15120;    // 1296
constexpr int WO_C1_W   = 16416;    // 2304
constexpr int WO_C2_W   = 18720;    // 2304
constexpr int WO_QKVL_B = 21024;    // 144
constexpr int WO_QKVR_B = 21168;    // 144
constexpr int WO_DWL_B  = 21312;    // 144
constexpr int WO_DWR_B  = 21456;    // 144
constexpr int WO_C1_B   = 21600;    // 48
constexpr int WO_C2_B   = 21648;    // 48  (= C1_B + 48, contiguous)
constexpr int WO_LN1W   = 21696;    // 48
constexpr int WO_LN1B   = 21744;    // 48
constexpr int WO_LN2W   = 21792;    // 48
constexpr int WO_LN2B   = 21840;    // 48
constexpr int WO_TEMP   = 21888;    // 3 (pad to 21952)
constexpr int WO_WQ     = 21952;    // 13824 (convQ_w fp32)
constexpr int WO_D0W    = 35776;    // 82944
constexpr int WO_D1W    = 118720;   // 82944
constexpr int WO_D2W    = 201664;   // 82944
constexpr int WO_BQ     = 284608;   // 48
constexpr int WO_B0     = 284656;   // 96
constexpr int WO_B1     = 284752;   // 96
constexpr int WO_B2     = 284848;   // 96
constexpr int WO_WPACK  = 284944;   // bf16 region! 124416 bf16 = 62208 floats
constexpr int WO_EFFB   = 409360;   // 48 (pad to 409424)
constexpr int WO_NQ     = 409424;   // 96 (sum of squares)
constexpr int WO_NKL    = 409520;   // 96
constexpr int WO_NKR    = 409616;   // 96
constexpr int WO_AR2L   = 409712;   // 1536
constexpr int WO_AL2R   = 411248;   // 1536
constexpr int WO_M1     = 412800;   // 4608
constexpr int WO_M2     = 417408;   // 4608 (= M1 + 4608, contiguous)
constexpr int WO_WQP    = 422016;   // bf16 region! 18432 bf16 = 9216 floats
constexpr int WO_PART   = 431232;   // 98304 (logits partials 12*32*256)
// end 529536 floats = 2,118,144 B

constexpr size_t ACT_BASE_BYTES = 2118144;

// bf16 activation region (element offsets)
constexpr size_t A_P  = 0;          // pre scratch (B*144*HW); later reused for qh
constexpr size_t A_Q1 = 9437184;    // qkv_l (B*144*HW)
constexpr size_t A_Q2 = 18874368;   // qkv_r (B*144*HW)
constexpr size_t A_QC = 28311552;   // QC (6586368)
// end 34897920 elems = 69.8 MB; total ws use ~72 MB

// ---------------- prep ----------------
struct PrepArgs {
  const void* src[25];
  int dst[25];
  int n[25];
};

__device__ __forceinline__ bool probe_bf16(const void* ln1w) {
  return ((const unsigned short*)ln1w)[0] == 0x3F80;
}

__global__ __launch_bounds__(256) void prep_k(PrepArgs a, float* __restrict__ wsf) {
  bool isb = probe_bf16(a.src[12]);
  int t = blockIdx.y;
  int i = blockIdx.x * 256 + threadIdx.x;
  if (i < a.n[t]) {
    float v = isb ? __bfloat162float(((const bf16*)a.src[t])[i])
                  : ((const float*)a.src[t])[i];
    wsf[a.dst[t] + i] = v;
  }
}

// fold convQ into dilated-conv weights, bf16, MFMA B-frag order, taps
// reordered by dy-group (ti): see dil_mfma_k decode.
__global__ __launch_bounds__(256) void effw2_k(const float* __restrict__ wsf,
                                               bf16* __restrict__ wpack) {
  int d  = blockIdx.x / 96;
  int ci = blockIdx.x % 96;
  __shared__ float wds[864];
  __shared__ float wqs[48 * 97];
  const int wdb = (d == 0) ? WO_D0W : (d == 1) ? WO_D1W : WO_D2W;
  for (int idx = threadIdx.x; idx < 864; idx += 256) {
    int m = idx / 9, tt = idx % 9;
    wds[idx] = wsf[wdb + (m * 96 + ci) * 9 + tt];
  }
  for (int idx = threadIdx.x; idx < 4608; idx += 256) {
    int co = idx / 96, m = idx % 96;
    wqs[co * 97 + m] = wsf[WO_WQ + co * 288 + d * 96 + m];
  }
  __syncthreads();
  int tco = threadIdx.x;
  if (tco < 432) {
    int t = tco / 48, co = tco % 48;
    float s = 0.f;
#pragma unroll 8
    for (int m = 0; m < 96; ++m) s += wqs[co * 97 + m] * wds[m * 9 + t];
    int trow = t / 3, dxi = t % 3;
    int ti = (trow == 0) ? (2 - d) * 3 + dxi
           : (trow == 1) ? 9 + d * 3 + dxi
                         : 18 + d * 3 + dxi;
    int kc = ci >> 5, j = ci & 7;
    int L = ((ci & 31) >> 3) * 16 + (co & 15);
    int nt = co >> 4;
    int f = (ti * 3 + kc) * 3 + nt;
    wpack[(size_t)f * 512 + L * 8 + j] = __float2bfloat16(s);
  }
}

__global__ __launch_bounds__(64) void effb_k(const float* __restrict__ wsf,
                                             float* __restrict__ effb) {
  int co = threadIdx.x;
  if (co >= 48) return;
  float s = wsf[WO_BQ + co];
  for (int m = 0; m < 96; ++m) {
    s += wsf[WO_WQ + co * 288 + m]       * wsf[WO_B0 + m];
    s += wsf[WO_WQ + co * 288 + 96 + m]  * wsf[WO_B1 + m];
    s += wsf[WO_WQ + co * 288 + 192 + m] * wsf[WO_B2 + m];
  }
  effb[co] = s;
}

// pack qkv 1x1 weights into MFMA B-frag order, K padded 48->64
__global__ __launch_bounds__(256) void wqp_k(const float* __restrict__ wsf,
                                             bf16* __restrict__ wqp) {
  int idx = blockIdx.x * 256 + threadIdx.x;
  if (idx >= 18432) return;
  int side = idx / 9216;
  int rem = idx % 9216;
  int nt = rem / 1024;
  int kt = (rem / 512) % 2;
  int e  = rem % 512;
  int L = e >> 3, j = e & 7;
  int o = nt * 16 + (L & 15);
  int kp = kt * 32 + (L >> 4) * 8 + j;
  int g = kp >> 4, r = kp & 15;
  float val = 0.f;
  if (r < 12) {
    int c = g * 12 + r;
    val = wsf[(side ? WO_QKVR_W : WO_QKVL_W) + o * 48 + c];
  }
  wqp[idx] = __float2bfloat16(val);
}

// ---------------- fused LN2d + qkv 1x1 (48->144) via MFMA, XN in LDS --------
__global__ __launch_bounds__(256) void lnqkv_k(
    const void* __restrict__ x, const void* __restrict__ probe,
    const float* __restrict__ lnw, const float* __restrict__ lnb,
    const bf16* __restrict__ wqp_side, const float* __restrict__ qb,
    bf16* __restrict__ pre) {
  __shared__ __align__(16) unsigned char LDSU[21504 + 18432];
  bf16* XNs = (bf16*)LDSU;                 // [64 px][72 kpad] bf16
  float2* red = (float2*)(LDSU + 9216);    // [4][64]
  bf16* Cs = (bf16*)LDSU;                  // [144][66] (aliases XNs later)
  bf16* W = (bf16*)(LDSU + 21504);         // 18432 B
  int tid = threadIdx.x;
  for (int i = tid; i < 1152; i += 256)
    ((uint4*)W)[i] = ((const uint4*)wqp_side)[i];

  int px = tid & 63;
  int w = tid >> 6;
  int p = blockIdx.x * 64 + px;
  int b = p >> 15;
  int pix = p & (HW - 1);
  size_t base = (size_t)b * CC * HW + pix;
  float v[12];
  if (probe_bf16(probe)) {
    const bf16* xp = (const bf16*)x + base;
#pragma unroll
    for (int c = 0; c < 12; ++c)
      v[c] = __bfloat162float(xp[(size_t)(w * 12 + c) * HW]);
  } else {
    const float* xp = (const float*)x + base;
#pragma unroll
    for (int c = 0; c < 12; ++c) v[c] = xp[(size_t)(w * 12 + c) * HW];
  }
  float s = 0.f, s2 = 0.f;
#pragma unroll
  for (int c = 0; c < 12; ++c) { s += v[c]; s2 += v[c] * v[c]; }
  red[w * 64 + px] = make_float2(s, s2);
  __syncthreads();
  float S = 0.f, S2 = 0.f;
#pragma unroll
  for (int i = 0; i < 4; ++i) {
    float2 r2 = red[i * 64 + px];
    S += r2.x; S2 += r2.y;
  }
  float mu = S * (1.f / 48.f);
  float var = S2 * (1.f / 48.f) - mu * mu;
  float rs = rsqrtf(var + 1e-6f);
  bf16 o16[16];
#pragma unroll
  for (int c = 0; c < 12; ++c)
    o16[c] = __float2bfloat16((v[c] - mu) * rs * lnw[w * 12 + c] + lnb[w * 12 + c]);
#pragma unroll
  for (int c = 12; c < 16; ++c) o16[c] = __float2bfloat16(0.f);
  *(uint4*)(XNs + px * 72 + w * 16) = *(uint4*)(o16);
  *(uint4*)(XNs + px * 72 + w * 16 + 8) = *(uint4*)(o16 + 8);
  __syncthreads();

  int L = tid & 63;
  int lo = L & 15, hi = L >> 4;
  const bf16* arow = XNs + (size_t)(w * 16 + lo) * 72 + hi * 8;
  short8 a0 = *(const short8*)(arow);
  short8 a1 = *(const short8*)(arow + 32);
  __syncthreads();
#pragma unroll
  for (int nt = 0; nt < 9; ++nt) {
    float bvv = qb[nt * 16 + lo];
    f32x4 acc = {bvv, bvv, bvv, bvv};
    acc = __builtin_amdgcn_mfma_f32_16x16x32_bf16(
        a0, *(const short8*)(W + (nt * 2 + 0) * 512 + L * 8), acc, 0, 0, 0);
    acc = __builtin_amdgcn_mfma_f32_16x16x32_bf16(
        a1, *(const short8*)(W + (nt * 2 + 1) * 512 + L * 8), acc, 0, 0, 0);
#pragma unroll
    for (int r = 0; r < 4; ++r)
      Cs[(nt * 16 + lo) * 66 + w * 16 + hi * 4 + r] = __float2bfloat16(acc[r]);
  }
  __syncthreads();
  int pix0 = (blockIdx.x * 64) & (HW - 1);
#pragma unroll
  for (int pass = 0; pass < 18; ++pass) {
    int o = pass * 8 + (tid >> 5);
    int px2 = (tid & 31) * 2;
    bf16 t2[2];
    t2[0] = Cs[o * 66 + px2];
    t2[1] = Cs[o * 66 + px2 + 1];
    *(unsigned*)(pre + ((size_t)(b * C3 + o)) * HW + pix0 + px2) = *(unsigned*)t2;
  }
}

// ---------------- depthwise 3x3, pad 1 — vectorized 8 px/thread ----------------
__global__ __launch_bounds__(256) void dw_k(
    const bf16* __restrict__ in, const float* __restrict__ w9,
    const float* __restrict__ bias, bf16* __restrict__ out) {
  int gid = blockIdx.x;
  int yt = gid & 15;
  int c = (gid >> 4) % C3;
  int b = gid / (16 * C3);
  int ry = threadIdx.x >> 5, xi = threadIdx.x & 31;
  int y = yt * 8 + ry;
  int x0 = xi * 8;
  const bf16* base = in + ((size_t)(b * C3 + c)) * HW;
  float wv[9];
#pragma unroll
  for (int t = 0; t < 9; ++t) wv[t] = w9[c * 9 + t];
  float bz = bias[c];
  float acc[8];
#pragma unroll
  for (int i = 0; i < 8; ++i) acc[i] = bz;
#pragma unroll
  for (int ky = 0; ky < 3; ++ky) {
    int yy = y + ky - 1;
    if ((unsigned)yy >= (unsigned)IMG_H) continue;
    const bf16* row = base + yy * IMG_W + x0;
    uint4 m = *(const uint4*)(row);
    float f[10];
    f[0] = (x0 > 0) ? __bfloat162float(row[-1]) : 0.f;
    f[9] = (x0 + 8 < IMG_W) ? __bfloat162float(row[8]) : 0.f;
    f[1] = __uint_as_float(m.x << 16);
    f[2] = __uint_as_float(m.x & 0xFFFF0000u);
    f[3] = __uint_as_float(m.y << 16);
    f[4] = __uint_as_float(m.y & 0xFFFF0000u);
    f[5] = __uint_as_float(m.z << 16);
    f[6] = __uint_as_float(m.z & 0xFFFF0000u);
    f[7] = __uint_as_float(m.w << 16);
    f[8] = __uint_as_float(m.w & 0xFFFF0000u);
    float w0 = wv[ky * 3], w1 = wv[ky * 3 + 1], w2 = wv[ky * 3 + 2];
#pragma unroll
    for (int i = 0; i < 8; ++i)
      acc[i] += w0 * f[i] + w1 * f[i + 1] + w2 * f[i + 2];
  }
  bf16 o[8];
#pragma unroll
  for (int i = 0; i < 8; ++i) o[i] = __float2bfloat16(acc[i]);
  *(uint4*)(out + ((size_t)(b * C3 + c)) * HW + y * IMG_W + x0) = *(uint4*)o;
}

// ---------------- channel-last transpose of Q channels ----------------
__global__ __launch_bounds__(256) void qc_k(const bf16* __restrict__ q1,
                                            const bf16* __restrict__ q2,
                                            bf16* __restrict__ qc) {
  int b = blockIdx.x >> 7;
  int y = blockIdx.x & 127;
  int half = blockIdx.y;
  int tid = threadIdx.x;
  int x0 = half * 128;
  int px = tid & 127;
  int cig = tid >> 7;
  __shared__ __align__(16) bf16 T[128][100];
#pragma unroll 8
  for (int k = 0; k < 48; ++k) {
    int ci = cig * 48 + k;
    const bf16* src = (ci < 48)
        ? q1 + (((size_t)(b * C3 + ci)) * IMG_H + y) * IMG_W
        : q2 + (((size_t)(b * C3 + ci - 48)) * IMG_H + y) * IMG_W;
    T[px][ci] = src[x0 + px];
  }
  __syncthreads();
  size_t rowbase = ((size_t)(b * IMG_H + y)) * XPW * 96 + (size_t)half * 12864;
#pragma unroll 1
  for (int i = 0; i < 13; ++i) {
    int e4 = i * 256 + tid;
    if (e4 >= 3216) break;
    int e = e4 * 4;
    int xp = (e + half * 12864) / 96;
    int ci = (e + half * 12864) % 96;
    int x = xp - XOFF;
    uint2 val;
    if ((unsigned)x < (unsigned)IMG_W) {
      val = *(const uint2*)(&T[x - x0][ci]);
    } else {
      val.x = 0u; val.y = 0u;
    }
    *(uint2*)(qc + rowbase + e) = val;
  }
}

// ---------------- tri-dilation conv via MFMA v4 ----------------
// v2 structure (256 thr, 4 waves, all 48 co, A read once) + XCD y-band swizzle
// + dy-grouped taps + grid 1024 (64 px/block -> 4 blocks/CU).
// grid 1024 = 8 xcd * (16 y) * (4 xt) * (2 b)
__global__ __launch_bounds__(256) void dil_mfma_k(
    const bf16* __restrict__ qc, const bf16* __restrict__ wp,
    const float* __restrict__ effb, bf16* __restrict__ qh) {
  __shared__ __align__(16) unsigned char LDSU[18432];  // W dbuf; Cs aliases
  bf16* Wb = (bf16*)LDSU;
  float* Cs = (float*)LDSU;   // [48][68] = 13056 B
  int bid = blockIdx.x;
  int xcd = bid & 7;
  int slot = bid >> 3;                  // 0..127
  int y = xcd * 16 + (slot & 15);
  int rest = slot >> 4;                 // 0..7
  int xt = rest & 3;
  int b = rest >> 2;
  int x0 = xt * 64;
  int tid = threadIdx.x;
  int L = tid & 63;
  int w = tid >> 6;
  int lo = L & 15, hi = L >> 4;

  f32x4 acc[3];
#pragma unroll
  for (int nt = 0; nt < 3; ++nt) {
    float bv = effb[nt * 16 + lo];
    acc[nt] = {bv, bv, bv, bv};
  }
  const size_t abase =
      ((size_t)(b * IMG_H + y) * XPW + XOFF + x0 + w * 16 + lo) * 96 + hi * 8;

  // stage tap 0 (9216 B = 576 uint4)
  {
    const uint4* src = (const uint4*)(wp);
    uint4* dst = (uint4*)(Wb);
    dst[tid] = src[tid];
    dst[tid + 256] = src[tid + 256];
    if (tid < 64) dst[tid + 512] = src[tid + 512];
  }
  __syncthreads();

#pragma unroll 1
  for (int ti = 0; ti < 27; ++ti) {
    if (ti + 1 < 27) {
      const uint4* src = (const uint4*)(wp + (ti + 1) * 4608);
      uint4* dst = (uint4*)(Wb + ((ti + 1) & 1) * 4608);
      dst[tid] = src[tid];
      dst[tid + 256] = src[tid + 256];
      if (tid < 64) dst[tid + 512] = src[tid + 512];
    }
    // dy-grouped decode: g=ti/3; g<3: D=6-2g, dy=-D; g<6: D=2(g-2), dy=0;
    // else D=2(g-5), dy=+D. dx=(ti%3-1)*D.
    int g = ti / 3, dxi = ti - g * 3;
    int D = (g < 3) ? (6 - 2 * g) : (g < 6) ? (2 * (g - 2)) : (2 * (g - 5));
    int dy = (g < 3) ? -D : (g < 6) ? 0 : D;
    int dx = (dxi - 1) * D;
    if ((unsigned)(y + dy) < (unsigned)IMG_H) {   // wave-uniform
      const bf16* wb = Wb + (ti & 1) * 4608;
      const bf16* ap = qc + abase + ((long)dy * XPW + dx) * 96;
#pragma unroll
      for (int kc = 0; kc < 3; ++kc) {
        short8 a = *(const short8*)(ap + kc * 32);
        const bf16* wk = wb + kc * 3 * 512 + L * 8;
#pragma unroll
        for (int nt = 0; nt < 3; ++nt) {
          acc[nt] = __builtin_amdgcn_mfma_f32_16x16x32_bf16(
              a, *(const short8*)(wk + nt * 512), acc[nt], 0, 0, 0);
        }
      }
    }
    __syncthreads();
  }

  // epilogue: Cs[48][68], then coalesced bf16 stores (48x64 px)
#pragma unroll
  for (int nt = 0; nt < 3; ++nt)
#pragma unroll
    for (int r = 0; r < 4; ++r)
      Cs[(nt * 16 + lo) * 68 + w * 16 + hi * 4 + r] = acc[nt][r];
  __syncthreads();
#pragma unroll
  for (int i = 0; i < 3; ++i) {
    int e4 = i * 256 + tid;
    int co = e4 >> 4;
    int px4 = (e4 & 15) * 4;
    const float* srcp = &Cs[co * 68 + px4];
    bf16 tmp[4];
    tmp[0] = __float2bfloat16(srcp[0]);
    tmp[1] = __float2bfloat16(srcp[1]);
    tmp[2] = __float2bfloat16(srcp[2]);
    tmp[3] = __float2bfloat16(srcp[3]);
    *(uint2*)(qh + (((size_t)(b * CC + co)) * IMG_H + y) * IMG_W + x0 + px4) =
        *(uint2*)tmp;
  }
}

// ---------------- reductions for attention ----------------
__device__ __forceinline__ float wave_sum(float v) {
#pragma unroll
  for (int off = 32; off > 0; off >>= 1) v += __shfl_down(v, off, 64);
  return v;
}

__device__ __forceinline__ float blo(unsigned u) {
  return __uint_as_float(u << 16);
}
__device__ __forceinline__ float bhi(unsigned u) {
  return __uint_as_float(u & 0xFFFF0000u);
}

__global__ __launch_bounds__(256) void rownorm_k(
    const bf16* __restrict__ qh, const bf16* __restrict__ qkvl,
    const bf16* __restrict__ qkvr, float* __restrict__ nq,
    float* __restrict__ nkl, float* __restrict__ nkr) {
  int id = blockIdx.x;
  int which = id / 96;
  int rid = id % 96;
  int b = rid / 48;
  int c = rid % 48;
  const bf16* ptr = (which == 0) ? qh + ((size_t)(b * CC + c)) * HW
                  : (which == 1) ? qkvl + ((size_t)(b * C3 + 48 + c)) * HW
                                 : qkvr + ((size_t)(b * C3 + 48 + c)) * HW;
  float s = 0.f;
#pragma unroll 2
  for (int it = 0; it < 16; ++it) {
    int n0 = (it * 256 + threadIdx.x) * 8;
    uint4 u = *(const uint4*)(ptr + n0);
    float a0 = blo(u.x), a1 = bhi(u.x), a2 = blo(u.y), a3 = bhi(u.y);
    float a4 = blo(u.z), a5 = bhi(u.z), a6 = blo(u.w), a7 = bhi(u.w);
    s += a0 * a0 + a1 * a1 + a2 * a2 + a3 * a3 + a4 * a4 + a5 * a5 +
         a6 * a6 + a7 * a7;
  }
  s = wave_sum(s);
  __shared__ float red[4];
  if ((threadIdx.x & 63) == 0) red[threadIdx.x >> 6] = s;
  __syncthreads();
  if (threadIdx.x == 0) {
    float tot = red[0] + red[1] + red[2] + red[3];
    float* dst = (which == 0) ? nq : (which == 1) ? nkl : nkr;
    dst[rid] = tot;
  }
}

// ---------------- logits via MFMA Gram: grid (12, 32) ----------------
__global__ __launch_bounds__(256) void logits_mfma_k(
    const bf16* __restrict__ qh, const bf16* __restrict__ qkvl,
    const bf16* __restrict__ qkvr, float* __restrict__ part) {
  int abh = blockIdx.x;
  int chunk = blockIdx.y;
  int a = abh / 6;
  int b = (abh / 3) % 2;
  int h = abh % 3;
  int tid = threadIdx.x;
  int L = tid & 63, w = tid >> 6;
  int lo = L & 15, hi = L >> 4;
  const bf16* qrow = qh + ((size_t)(b * CC + h * 16 + lo)) * HW;
  const bf16* krow =
      ((a == 0) ? qkvr : qkvl) + ((size_t)(b * C3 + 48 + h * 16 + lo)) * HW;
  int px0 = chunk * 1024 + w * 256 + hi * 8;
  f32x4 acc = {0.f, 0.f, 0.f, 0.f};
#pragma unroll
  for (int s = 0; s < 8; ++s) {
    short8 av = *(const short8*)(qrow + px0 + s * 32);
    short8 bv = *(const short8*)(krow + px0 + s * 32);
    acc = __builtin_amdgcn_mfma_f32_16x16x32_bf16(av, bv, acc, 0, 0, 0);
  }
  __shared__ float red[4][256];
#pragma unroll
  for (int r = 0; r < 4; ++r) red[w][(hi * 4 + r) * 16 + lo] = acc[r];
  __syncthreads();
  float sum = red[0][tid] + red[1][tid] + red[2][tid] + red[3][tid];
  part[((size_t)abh * 32 + chunk) * 256 + tid] = sum;
}

__global__ __launch_bounds__(256) void logits_red_k(
    const float* __restrict__ part, const float* __restrict__ nq,
    const float* __restrict__ nkl, const float* __restrict__ nkr,
    const float* __restrict__ temp, float* __restrict__ logr2l,
    float* __restrict__ logl2r) {
  int abh = blockIdx.x;
  int a = abh / 6, b = (abh / 3) % 2, h = abh % 3;
  int t = threadIdx.x;
  int i = t >> 4, j = t & 15;
  float s = 0.f;
  const float* p = part + (size_t)abh * 32 * 256 + t;
#pragma unroll 8
  for (int c = 0; c < 32; ++c) s += p[c * 256];
  float qn = fmaxf(sqrtf(nq[b * 48 + h * 16 + i]), 1e-12f);
  float kn = fmaxf(sqrtf(((a == 0) ? nkr : nkl)[b * 48 + h * 16 + j]), 1e-12f);
  float val = s / (qn * kn) * temp[h];
  ((a == 0) ? logr2l : logl2r)[b * 768 + h * 256 + i * 16 + j] = val;
}

// softmax over j (16) + fold conv1/conv2 into A -> M1/M2
__global__ __launch_bounds__(256) void softmaxM_k(float* __restrict__ wsf) {
  int tid = threadIdx.x;
  __shared__ float A1[1536], A2[1536];
  if (tid < 192) {
    const float* p = wsf + ((tid < 96) ? WO_AR2L : WO_AL2R) + (tid % 96) * 16;
    float* dst = ((tid < 96) ? A1 : A2) + (tid % 96) * 16;
    float m = -1e30f;
#pragma unroll
    for (int j = 0; j < 16; ++j) m = fmaxf(m, p[j]);
    float s = 0.f;
    float e[16];
#pragma unroll
    for (int j = 0; j < 16; ++j) {
      e[j] = expf(p[j] - m);
      s += e[j];
    }
    float inv = 1.f / s;
#pragma unroll
    for (int j = 0; j < 16; ++j) dst[j] = e[j] * inv;
  }
  __syncthreads();
#pragma unroll 1
  for (int idx = tid; idx < 4608; idx += 256) {
    int b = idx / 2304;
    int r = idx % 2304;
    int o = r / 48;
    int cp = r % 48;
    int h = cp >> 4, j = cp & 15;
    const float* a1 = &A1[((b * 3 + h) * 16) * 16 + j];
    const float* a2 = &A2[((b * 3 + h) * 16) * 16 + j];
    float s1 = 0.f, s2 = 0.f;
#pragma unroll
    for (int i = 0; i < 16; ++i) {
      s1 += wsf[WO_C1_W + o * 48 + h * 16 + i] * a1[i * 16];
      s2 += wsf[WO_C2_W + o * 48 + h * 16 + i] * a2[i * 16];
    }
    wsf[WO_M1 + idx] = s1;
    wsf[WO_M2 + idx] = s2;
  }
}

// ---------------- fused M@V + residual -> out (both sides, z=side) ----------
__global__ __launch_bounds__(256) void attn_out2_k(
    const bf16* __restrict__ q1, const bf16* __restrict__ q2,
    const void* __restrict__ x1, const void* __restrict__ x2,
    const void* __restrict__ probe, const float* __restrict__ Mall,
    const float* __restrict__ cball, void* __restrict__ out) {
  int side = blockIdx.z;
  const bf16* qkv = side ? q2 : q1;
  const void* x = side ? x2 : x1;
  const float* M = Mall + side * 4608;
  const float* cb = cball + side * 48;
  int tid = threadIdx.x;
  int p = blockIdx.x * 256 + tid;
  int b = __builtin_amdgcn_readfirstlane(p >> 15);
  int pix = p & (HW - 1);
  int o0 = blockIdx.y * 16;
  bool isb = probe_bf16(probe);

  float v[CC];
  const bf16* vb = qkv + ((size_t)(b * C3 + 96)) * HW + pix;
#pragma unroll
  for (int c = 0; c < CC; ++c) v[c] = __bfloat162float(vb[(size_t)c * HW]);

  const float* Mb = M + b * 2304;
  size_t base = (size_t)b * CC * HW + pix;
  float res[16];
#pragma unroll 2
  for (int o = 0; o < 16; ++o) {
    float acc = cb[o0 + o];
    const float* mrow = Mb + (o0 + o) * 48;
#pragma unroll
    for (int c = 0; c < CC; ++c) acc += mrow[c] * v[c];
    res[o] = acc;
  }
  size_t obase = (size_t)side * BB * CC * HW + base + (size_t)o0 * HW;
  if (isb) {
    const bf16* xp = (const bf16*)x + base + (size_t)o0 * HW;
    bf16* op = (bf16*)out + obase;
#pragma unroll
    for (int o = 0; o < 16; ++o)
      op[(size_t)o * HW] =
          __float2bfloat16(res[o] + __bfloat162float(xp[(size_t)o * HW]));
  } else {
    const float* xp = (const float*)x + base + (size_t)o0 * HW;
    float* op = (float*)out + obase;
#pragma unroll
    for (int o = 0; o < 16; ++o) op[(size_t)o * HW] = res[o] + xp[(size_t)o * HW];
  }
}

// ---------------- launch ----------------
extern "C" void kernel_launch(void* const* d_in, const int* in_sizes, int n_in,
                              void* d_out, int out_size, void* d_ws, size_t ws_size,
                              hipStream_t stream) {
  (void)in_sizes; (void)n_in; (void)out_size; (void)ws_size;
  const void* x_l = d_in[0];
  const void* x_r = d_in[1];
  const void* probe = d_in[2];
  float* wsf = (float*)d_ws;
  bf16* wpack = (bf16*)(wsf + WO_WPACK);
  bf16* wqp = (bf16*)(wsf + WO_WQP);
  bf16* act = (bf16*)((char*)d_ws + ACT_BASE_BYTES);
  bf16* P  = act + A_P;
  bf16* Q1 = act + A_Q1;
  bf16* Q2 = act + A_Q2;
  bf16* QC = act + A_QC;
  bf16* qh = P;

  PrepArgs pa;
  const int srcIdx[25] = {6, 8, 10, 12, 22, 24, 7, 9, 11, 13, 23, 25,
                          2, 3, 4, 5, 26, 20, 14, 16, 18, 21, 15, 17, 19};
  const int dstOff[25] = {WO_QKVL_W, WO_QKVR_W, WO_DWL_W, WO_DWR_W, WO_C1_W, WO_C2_W,
                          WO_QKVL_B, WO_QKVR_B, WO_DWL_B, WO_DWR_B, WO_C1_B, WO_C2_B,
                          WO_LN1W, WO_LN1B, WO_LN2W, WO_LN2B, WO_TEMP,
                          WO_WQ, WO_D0W, WO_D1W, WO_D2W, WO_BQ, WO_B0, WO_B1, WO_B2};
  const int ns[25] = {6912, 6912, 1296, 1296, 2304, 2304, 144, 144, 144, 144,
                      48, 48, 48, 48, 48, 48, 3,
                      13824, 82944, 82944, 82944, 48, 96, 96, 96};
  for (int i = 0; i < 25; ++i) {
    pa.src[i] = d_in[srcIdx[i]];
    pa.dst[i] = dstOff[i];
    pa.n[i] = ns[i];
  }
  prep_k<<<dim3(324, 25), 256, 0, stream>>>(pa, wsf);

  effw2_k<<<288, 256, 0, stream>>>(wsf, wpack);
  effb_k<<<1, 64, 0, stream>>>(wsf, wsf + WO_EFFB);
  wqp_k<<<72, 256, 0, stream>>>(wsf, wqp);

  lnqkv_k<<<1024, 256, 0, stream>>>(x_l, probe, wsf + WO_LN1W, wsf + WO_LN1B,
                                    wqp, wsf + WO_QKVL_B, P);
  dw_k<<<BB * C3 * 16, 256, 0, stream>>>(P, wsf + WO_DWL_W, wsf + WO_DWL_B, Q1);
  lnqkv_k<<<1024, 256, 0, stream>>>(x_r, probe, wsf + WO_LN2W, wsf + WO_LN2B,
                                    wqp + 9216, wsf + WO_QKVR_B, P);
  dw_k<<<BB * C3 * 16, 256, 0, stream>>>(P, wsf + WO_DWR_W, wsf + WO_DWR_B, Q2);

  qc_k<<<dim3(BB * IMG_H, 2), 256, 0, stream>>>(Q1, Q2, QC);

  // P dead; qh aliases it
  dil_mfma_k<<<1024, 256, 0, stream>>>(QC, wpack, wsf + WO_EFFB, qh);

  rownorm_k<<<288, 256, 0, stream>>>(qh, Q1, Q2, wsf + WO_NQ,
                                     wsf + WO_NKL, wsf + WO_NKR);
  logits_mfma_k<<<dim3(12, 32), 256, 0, stream>>>(qh, Q1, Q2, wsf + WO_PART);
  logits_red_k<<<12, 256, 0, stream>>>(wsf + WO_PART, wsf + WO_NQ,
                                       wsf + WO_NKL, wsf + WO_NKR,
                                       wsf + WO_TEMP, wsf + WO_AR2L,
                                       wsf + WO_AL2R);
  softmaxM_k<<<1, 256, 0, stream>>>(wsf);

  attn_out2_k<<<dim3(256, 3, 2), 256, 0, stream>>>(
      Q1, Q2, x_l, x_r, probe, wsf + WO_M1, wsf + WO_C1_B, d_out);
}